// Round 5
// baseline (245.478 us; speedup 1.0000x reference)
//
#include <hip/hip_runtime.h>
#include <math.h>

// B=16,H=14,W=14,D=512, L=32, HID=512, A=512.
// R17: one kernel, grid 512x512thr, spin grid-barrier WITHOUT threadfence.
// R16 post-mortem: 85us with VALU 9.5% / HBM 2.5% / 3.5 lines-in-flight per CU.
// Root cause theory: per-block __threadfence at each barrier = buffer_wbl2 +
// buffer_inv per block (512 L2 invalidates/launch) -> L2 locality destroyed ->
// mid re-streams ~51MB/XCD from L3/HBM latency-bound. (R13 cg::sync, same
// fences, also 85us; R12's 3 kernels = 3 fences total ran ~40us.)
// Fix: NO fences. Cross-phase data (hlin/ctx, ~2MB) uses agent-scope relaxed
// atomics (sc0/sc1 -> bypass non-coherent per-XCD L2); ordering comes from the
// acq_rel barrier counter. L2 stays valid for maps/W across phases.
// Also: blocks 256..511 prefetch maps (XCD-affine) + W_co into L2 during
// gemm1; mid runs 1 l per block (512 blocks, 16 waves/CU).
// Co-residency: LDS 66.4KB -> 2 blocks/CU, 512 blocks == 2*256 capacity ✓.

typedef __attribute__((ext_vector_type(8))) short short8;
typedef __attribute__((ext_vector_type(4))) float f32x4;

__device__ unsigned g_bar2 = 0;   // .bss, zero at load, monotone across replays

__device__ __forceinline__ void grid_barrier512() {
    __syncthreads();                       // block's stores issued; tid0 proceeds
    if (threadIdx.x == 0) {
        // acq_rel RMW: release prior (coherent) stores, no L2 writeback/inv
        unsigned old = __hip_atomic_fetch_add(&g_bar2, 1u, __ATOMIC_ACQ_REL,
                                              __HIP_MEMORY_SCOPE_AGENT);
        const unsigned tgt = (old & ~511u) + 512u;
        while (__hip_atomic_load(&g_bar2, __ATOMIC_ACQUIRE,
                                 __HIP_MEMORY_SCOPE_AGENT) < tgt)
            __builtin_amdgcn_s_sleep(8);
    }
    __syncthreads();
}

// coherent (L2-bypassing) scalar access for cross-XCD-communicated buffers
__device__ __forceinline__ float cload(const float* p) {
    return __hip_atomic_load(p, __ATOMIC_RELAXED, __HIP_MEMORY_SCOPE_AGENT);
}
__device__ __forceinline__ void cstore(float* p, float v) {
    __hip_atomic_store(p, v, __ATOMIC_RELAXED, __HIP_MEMORY_SCOPE_AGENT);
}

__device__ __forceinline__ unsigned f2bf_u(float x) {
    union { float f; unsigned u; } c; c.f = x;
    return (c.u + 0x7FFFu + ((c.u >> 16) & 1u)) >> 16;   // RNE, finite inputs
}
__device__ __forceinline__ unsigned pack2(float lo, float hi) {
    return f2bf_u(lo) | (f2bf_u(hi) << 16);
}
__device__ __forceinline__ uint4 pack8(const float4 a, const float4 b) {
    uint4 r;
    r.x = pack2(a.x, a.y); r.y = pack2(a.z, a.w);
    r.z = pack2(b.x, b.y); r.w = pack2(b.z, b.w);
    return r;
}
__device__ __forceinline__ float rdot4(const float4 f, const float4 g, const float4 w) {
    return fmaxf(f.x+g.x, 0.f)*w.x + fmaxf(f.y+g.y, 0.f)*w.y
         + fmaxf(f.z+g.z, 0.f)*w.z + fmaxf(f.w+g.w, 0.f)*w.w;
}
__device__ __forceinline__ float wave_sum(float v) {
    v += __shfl_down(v, 32); v += __shfl_down(v, 16); v += __shfl_down(v, 8);
    v += __shfl_down(v, 4);  v += __shfl_down(v, 2);  v += __shfl_down(v, 1);
    return v;   // lane 0 holds the sum
}

// ---- GEMM phase (blocks 0..255): C = A . B^T + bias[n] [* hmul] ----
// 512 threads: tile (m0,n0) 32x32; 8 waves split K (2 chunks of 32) + LDS reduce.
// CLOADA: A read via coherent scalar loads (ctx from other XCDs).
// CSTOREC: C written via coherent stores (hlin consumed by other XCDs).
template<int HMUL, int CLOADA, int CSTOREC>
__device__ __forceinline__ void gemm_body(char* smem,
    const float* __restrict__ Af, const float* __restrict__ Bf,
    const float* __restrict__ bias, const float* __restrict__ hmul,
    float* __restrict__ C)
{
    uint4* As = (uint4*)smem;               // 2048 slots (32KB)
    uint4* Bs = (uint4*)(smem + 32768);     // 2048 slots (32KB)
    float* red = (float*)smem;              // overlays As after sync (32KB)
    const int tid = threadIdx.x, bid = blockIdx.x;

    const int m0 = (bid >> 4) * 32, n0 = (bid & 15) * 32;
    #pragma unroll
    for (int j = 0; j < 4; ++j) {
        const int S = tid + 512 * j;
        const int i = S >> 6, ln = S & 63;
        const int t = i & 1, s = i >> 1;
        const int row  = t * 16 + (ln & 15);
        const int col8 = s * 4 + (ln >> 4);
        const float* ap = Af + (size_t)(m0 + row) * 512 + col8 * 8;
        const float* bp = Bf + (size_t)(n0 + row) * 512 + col8 * 8;
        float4 av0, av1;
        if (CLOADA) {
            av0.x = cload(ap+0); av0.y = cload(ap+1);
            av0.z = cload(ap+2); av0.w = cload(ap+3);
            av1.x = cload(ap+4); av1.y = cload(ap+5);
            av1.z = cload(ap+6); av1.w = cload(ap+7);
        } else {
            av0 = *(const float4*)ap; av1 = *(const float4*)(ap + 4);
        }
        As[S] = pack8(av0, av1);
        Bs[S] = pack8(*(const float4*)bp, *(const float4*)(bp + 4));
    }
    __syncthreads();

    const int w = tid >> 6, ln = tid & 63;
    f32x4 acc[4];                            // fo = tm*2+tn
    #pragma unroll
    for (int fo = 0; fo < 4; ++fo) acc[fo] = (f32x4){0.f,0.f,0.f,0.f};
    #pragma unroll
    for (int sl = 0; sl < 2; ++sl) {
        const int s = 2 * w + sl;            // k-chunk 0..15
        const short8 a0 = *(const short8*)&As[(2*s+0)*64 + ln];
        const short8 a1 = *(const short8*)&As[(2*s+1)*64 + ln];
        const short8 b0 = *(const short8*)&Bs[(2*s+0)*64 + ln];
        const short8 b1 = *(const short8*)&Bs[(2*s+1)*64 + ln];
        acc[0] = __builtin_amdgcn_mfma_f32_16x16x32_bf16(a0, b0, acc[0], 0, 0, 0);
        acc[1] = __builtin_amdgcn_mfma_f32_16x16x32_bf16(a0, b1, acc[1], 0, 0, 0);
        acc[2] = __builtin_amdgcn_mfma_f32_16x16x32_bf16(a1, b0, acc[2], 0, 0, 0);
        acc[3] = __builtin_amdgcn_mfma_f32_16x16x32_bf16(a1, b1, acc[3], 0, 0, 0);
    }
    __syncthreads();                         // done reading As/Bs
    #pragma unroll
    for (int fo = 0; fo < 4; ++fo)
        #pragma unroll
        for (int r = 0; r < 4; ++r)
            red[w*1024 + fo*256 + r*64 + ln] = acc[fo][r];
    __syncthreads();
    #pragma unroll
    for (int jj = 0; jj < 2; ++jj) {
        const int o = tid + 512 * jj;        // 0..1023 outputs
        float v = 0.f;
        #pragma unroll
        for (int ww = 0; ww < 8; ++ww) v += red[ww*1024 + o];
        const int fo = o >> 8, r = (o >> 6) & 3, l2 = o & 63;
        // C/D layout: col = lane&15, row = (lane>>4)*4 + reg [m89-verified]
        const int m = m0 + (fo >> 1) * 16 + ((l2 >> 4) << 2) + r;
        const int n = n0 + (fo & 1) * 16 + (l2 & 15);
        v += bias[n];
        if (HMUL) v *= hmul[(size_t)m * 512 + n];
        if (CSTOREC) cstore(&C[(size_t)m * 512 + n], v);
        else         C[(size_t)m * 512 + n] = v;
    }
}

// ---- prefetch phase (blocks 256..511, runs during gemm1) ----
// Warm this XCD's L2: maps[b-pair] (800KB) + the W_co rows gemm2 tiles on this
// XCD will read. Normal cached loads allocate in the local L2.
__device__ __forceinline__ void prefetch_body(
    const float* __restrict__ maps, const float* __restrict__ W_co)
{
    const int tid = threadIdx.x, bx = blockIdx.x;
    const int xcd = bx & 7, h = (bx >> 3) & 31;   // helper 0..31 on this xcd
    float acc = 0.f;
    // maps rows of b = 2*xcd, 2*xcd+1 : 200704 contiguous floats
    const float* mp = maps + (size_t)(2 * xcd) * 196 * 512;
    for (size_t i = (size_t)h * 512 + tid; i < 200704; i += 16384)
        acc += mp[i];
    // W_co rows used by gemm2 tiles with bid&7==xcd: n0 = xcd*32 and (xcd+8)*32
    const float* wc0 = W_co + (size_t)(xcd * 32) * 512;        // 16384 floats
    const float* wc1 = W_co + (size_t)((xcd + 8) * 32) * 512;  // 16384 floats
    {
        const size_t i = (size_t)h * 512 + tid;                // one pass
        acc += wc0[i] + wc1[i];
    }
    asm volatile("" :: "v"(acc));   // keep loads alive (no DCE)
}

// ---- mid phase (all 512 blocks): block owns one (b, l) ----
__device__ __forceinline__ void mid_body(float* smrow,
    const float* __restrict__ maps, const float* __restrict__ hlin,
    const float* __restrict__ W_rect, const float* __restrict__ b_rect,
    float* __restrict__ attn_out, float* __restrict__ ctx_out)
{
    const int tid = threadIdx.x, bx = blockIdx.x;
    const int xcd = bx & 7, j = bx >> 3;           // j 0..63
    const int b = (xcd << 1) | (j & 1);            // maps[b-pair] L2-resident
    const int l = j >> 1;                          // 0..31
    const int w = tid >> 6, lane = tid & 63;
    const int a_lo = lane * 4, a_hi = 256 + lane * 4;

    // hlin row l: written by gemm1 on other XCDs -> coherent scalar loads
    const float* hp = hlin + ((size_t)b * 32 + l) * 512;
    float4 g_lo, g_hi;
    g_lo.x = cload(hp + a_lo);     g_lo.y = cload(hp + a_lo + 1);
    g_lo.z = cload(hp + a_lo + 2); g_lo.w = cload(hp + a_lo + 3);
    g_hi.x = cload(hp + a_hi);     g_hi.y = cload(hp + a_hi + 1);
    g_hi.z = cload(hp + a_hi + 2); g_hi.w = cload(hp + a_hi + 3);
    const float4 w_lo = *(const float4*)(W_rect + a_lo);
    const float4 w_hi = *(const float4*)(W_rect + a_hi);
    const float br = b_rect[0];
    const float* mb = maps + (size_t)b * 196 * 512;

    // scores: wave w owns p === w (mod 8); 2 rows per iter for load ILP
    for (int p0 = w; p0 < 196; p0 += 16) {
        const int p1 = p0 + 8;
        const float* fr0 = mb + (size_t)p0 * 512;
        const float4 fa0 = *(const float4*)(fr0 + a_lo);
        const float4 fb0 = *(const float4*)(fr0 + a_hi);
        float sA = rdot4(fa0, g_lo, w_lo) + rdot4(fb0, g_hi, w_hi);
        float sB = 0.f;
        if (p1 < 196) {
            const float* fr1 = mb + (size_t)p1 * 512;
            const float4 fa1 = *(const float4*)(fr1 + a_lo);
            const float4 fb1 = *(const float4*)(fr1 + a_hi);
            sB = rdot4(fa1, g_lo, w_lo) + rdot4(fb1, g_hi, w_hi);
        }
        sA = wave_sum(sA);
        sB = wave_sum(sB);
        if (lane == 0) {
            smrow[p0] = sA + br;
            if (p1 < 196) smrow[p1] = sB + br;
        }
    }
    __syncthreads();

    // softmax over 196 pixels: wave 0
    if (w == 0) {
        float v[4];
        #pragma unroll
        for (int i = 0; i < 4; ++i) {
            const int p = lane + 64 * i;
            v[i] = (p < 196) ? smrow[p] : -INFINITY;
        }
        float m = fmaxf(fmaxf(v[0], v[1]), fmaxf(v[2], v[3]));
        for (int off = 32; off > 0; off >>= 1) m = fmaxf(m, __shfl_down(m, off));
        m = __shfl(m, 0);
        float e[4], ssum = 0.f;
        #pragma unroll
        for (int i = 0; i < 4; ++i) {
            const int p = lane + 64 * i;
            e[i] = (p < 196) ? __expf(v[i] - m) : 0.f;
            ssum += e[i];
        }
        for (int off = 32; off > 0; off >>= 1) ssum += __shfl_down(ssum, off);
        ssum = __shfl(ssum, 0);
        const float inv = 1.f / ssum;
        float* ao = attn_out + ((size_t)b * 32 + l) * 196;
        #pragma unroll
        for (int i = 0; i < 4; ++i) {
            const int p = lane + 64 * i;
            if (p < 196) {
                const float at = e[i] * inv;
                smrow[p] = at;
                ao[p] = at;
            }
        }
    }
    __syncthreads();

    // ctx: thread owns col d = tid; maps row-stream is L2-hot (scores+prefetch)
    {
        const int d = tid;
        float a0=0.f, a1=0.f, a2=0.f, a3=0.f;
        for (int p = 0; p < 196; p += 4) {
            const float f0 = mb[(size_t)(p+0)*512 + d];
            const float f1 = mb[(size_t)(p+1)*512 + d];
            const float f2 = mb[(size_t)(p+2)*512 + d];
            const float f3 = mb[(size_t)(p+3)*512 + d];
            a0 += smrow[p+0]*f0; a1 += smrow[p+1]*f1;
            a2 += smrow[p+2]*f2; a3 += smrow[p+3]*f3;
        }
        // ctx row consumed by gemm2 on other XCDs -> coherent store
        cstore(ctx_out + ((size_t)b * 32 + l) * 512 + d, (a0 + a1) + (a2 + a3));
    }
}

__global__ __launch_bounds__(512) void coatt_fused(
    const float* __restrict__ maps, const float* __restrict__ hiddens,
    const float* __restrict__ W_hidden, const float* __restrict__ b_hidden,
    const float* __restrict__ W_rect, const float* __restrict__ b_rect,
    const float* __restrict__ W_co, const float* __restrict__ b_co,
    float* __restrict__ out_co, float* __restrict__ attn_out,
    float* __restrict__ hlin_ws, float* __restrict__ ctx_ws)
{
    __shared__ __align__(16) char smem[65536];
    __shared__ __align__(16) float smrow[208];     // LDS total ~66.4KB -> 2 blocks/CU

    const int bx = blockIdx.x;
    // Phase 1: gemm1 on blocks 0..255; L2 prefetch on 256..511
    if (bx < 256)
        gemm_body<0, 0, 1>(smem, hiddens, W_hidden, b_hidden,
                           (const float*)nullptr, hlin_ws);
    else
        prefetch_body(maps, W_co);
    grid_barrier512();
    // Phase 2: all 512 blocks, one (b,l) each
    mid_body(smrow, maps, hlin_ws, W_rect, b_rect, attn_out, ctx_ws);
    grid_barrier512();
    // Phase 3: gemm2 on blocks 0..255
    if (bx < 256)
        gemm_body<1, 1, 0>(smem, ctx_ws, W_co, b_co, hiddens, out_co);
}

extern "C" void kernel_launch(void* const* d_in, const int* in_sizes, int n_in,
                              void* d_out, int out_size, void* d_ws, size_t ws_size,
                              hipStream_t stream)
{
    const float* maps     = (const float*)d_in[0];
    const float* hiddens  = (const float*)d_in[1];
    const float* W_hidden = (const float*)d_in[2];
    const float* b_hidden = (const float*)d_in[3];
    const float* W_rect   = (const float*)d_in[4];
    const float* b_rect   = (const float*)d_in[5];
    const float* W_co     = (const float*)d_in[6];
    const float* b_co     = (const float*)d_in[7];

    float* out_co   = (float*)d_out;                    // (512,512)
    float* out_attn = out_co + (size_t)512 * 512;       // (512,196)
    float* hlin     = (float*)d_ws;                     // (512,512) fp32
    float* ctx      = hlin + (size_t)512 * 512;         // (512,512) fp32

    hipLaunchKernelGGL(coatt_fused, dim3(512), dim3(512), 0, stream,
                       maps, hiddens, W_hidden, b_hidden, W_rect, b_rect,
                       W_co, b_co, out_co, out_attn, hlin, ctx);
}

// Round 6
// 105.945 us; speedup vs baseline: 2.3170x; 2.3170x over previous
//
#include <hip/hip_runtime.h>
#include <math.h>

// B=16,H=14,W=14,D=512, L=32, HID=512, A=512.
// R18: back to 3 plain kernels (graph nodes are ~2us each; R12's real cost was
// mid's 51MB maps re-fetch, not node count). Fused variants are abandoned:
// every grid-barrier implementation (cg::sync R13, acquire-spin R16/R17) polls
// with agent-scope ACQUIRE loads -> buffer_inv per poll -> continuous per-XCD
// L2 invalidation storm -> 85-190us. Kernel dispatch boundaries give exactly
// one acquire/release pair each, for free, with guaranteed correctness.
// Changes vs R12:
//  - mid: XCD-affine b mapping (bx&7 -> maps[b-pair] 800KB resident in that
//    XCD's 4MB L2; scores pass fetches from HBM once, ctx pass hits L2).
//  - mid: wave-per-p scores with direct float4 loads (no ftile/red LDS
//    machinery: LDS 1.7KB -> 4 blocks/CU = 32 waves/CU; 0 bank conflicts).
//  - GEMMs: 512-thread 8-wave split-K bodies (R16-proven).

typedef __attribute__((ext_vector_type(8))) short short8;
typedef __attribute__((ext_vector_type(4))) float f32x4;

__device__ __forceinline__ unsigned f2bf_u(float x) {
    union { float f; unsigned u; } c; c.f = x;
    return (c.u + 0x7FFFu + ((c.u >> 16) & 1u)) >> 16;   // RNE, finite inputs
}
__device__ __forceinline__ unsigned pack2(float lo, float hi) {
    return f2bf_u(lo) | (f2bf_u(hi) << 16);
}
__device__ __forceinline__ uint4 pack8(const float4 a, const float4 b) {
    uint4 r;
    r.x = pack2(a.x, a.y); r.y = pack2(a.z, a.w);
    r.z = pack2(b.x, b.y); r.w = pack2(b.z, b.w);
    return r;
}
__device__ __forceinline__ float rdot4(const float4 f, const float4 g, const float4 w) {
    return fmaxf(f.x+g.x, 0.f)*w.x + fmaxf(f.y+g.y, 0.f)*w.y
         + fmaxf(f.z+g.z, 0.f)*w.z + fmaxf(f.w+g.w, 0.f)*w.w;
}
__device__ __forceinline__ float wave_sum(float v) {
    v += __shfl_down(v, 32); v += __shfl_down(v, 16); v += __shfl_down(v, 8);
    v += __shfl_down(v, 4);  v += __shfl_down(v, 2);  v += __shfl_down(v, 1);
    return v;   // lane 0 holds the sum
}

// ---- GEMM: C = A(512,512)_f32 . B(512,512)_f32^T + bias[n] [* hmul] ----
// 512 threads: tile (m0,n0) 32x32; 8 waves split K (2 chunks of 32) + LDS reduce.
template<int HMUL>
__global__ __launch_bounds__(512) void gemm_kernel(
    const float* __restrict__ Af, const float* __restrict__ Bf,
    const float* __restrict__ bias, const float* __restrict__ hmul,
    float* __restrict__ C)
{
    __shared__ __align__(16) char smem[65536];
    uint4* As = (uint4*)smem;               // 2048 slots (32KB)
    uint4* Bs = (uint4*)(smem + 32768);     // 2048 slots (32KB)
    float* red = (float*)smem;              // overlays As after sync (32KB)
    const int tid = threadIdx.x, bid = blockIdx.x;

    const int m0 = (bid >> 4) * 32, n0 = (bid & 15) * 32;
    #pragma unroll
    for (int j = 0; j < 4; ++j) {
        const int S = tid + 512 * j;
        const int i = S >> 6, ln = S & 63;
        const int t = i & 1, s = i >> 1;
        const int row  = t * 16 + (ln & 15);
        const int col8 = s * 4 + (ln >> 4);
        const float* ap = Af + (size_t)(m0 + row) * 512 + col8 * 8;
        const float* bp = Bf + (size_t)(n0 + row) * 512 + col8 * 8;
        As[S] = pack8(*(const float4*)ap, *(const float4*)(ap + 4));
        Bs[S] = pack8(*(const float4*)bp, *(const float4*)(bp + 4));
    }
    __syncthreads();

    const int w = tid >> 6, ln = tid & 63;
    f32x4 acc[4];                            // fo = tm*2+tn
    #pragma unroll
    for (int fo = 0; fo < 4; ++fo) acc[fo] = (f32x4){0.f,0.f,0.f,0.f};
    #pragma unroll
    for (int sl = 0; sl < 2; ++sl) {
        const int s = 2 * w + sl;            // k-chunk 0..15
        const short8 a0 = *(const short8*)&As[(2*s+0)*64 + ln];
        const short8 a1 = *(const short8*)&As[(2*s+1)*64 + ln];
        const short8 b0 = *(const short8*)&Bs[(2*s+0)*64 + ln];
        const short8 b1 = *(const short8*)&Bs[(2*s+1)*64 + ln];
        acc[0] = __builtin_amdgcn_mfma_f32_16x16x32_bf16(a0, b0, acc[0], 0, 0, 0);
        acc[1] = __builtin_amdgcn_mfma_f32_16x16x32_bf16(a0, b1, acc[1], 0, 0, 0);
        acc[2] = __builtin_amdgcn_mfma_f32_16x16x32_bf16(a1, b0, acc[2], 0, 0, 0);
        acc[3] = __builtin_amdgcn_mfma_f32_16x16x32_bf16(a1, b1, acc[3], 0, 0, 0);
    }
    __syncthreads();                         // done reading As/Bs
    #pragma unroll
    for (int fo = 0; fo < 4; ++fo)
        #pragma unroll
        for (int r = 0; r < 4; ++r)
            red[w*1024 + fo*256 + r*64 + ln] = acc[fo][r];
    __syncthreads();
    #pragma unroll
    for (int jj = 0; jj < 2; ++jj) {
        const int o = tid + 512 * jj;        // 0..1023 outputs
        float v = 0.f;
        #pragma unroll
        for (int ww = 0; ww < 8; ++ww) v += red[ww*1024 + o];
        const int fo = o >> 8, r = (o >> 6) & 3, l2 = o & 63;
        // C/D layout: col = lane&15, row = (lane>>4)*4 + reg [m89-verified]
        const int m = m0 + (fo >> 1) * 16 + ((l2 >> 4) << 2) + r;
        const int n = n0 + (fo & 1) * 16 + (l2 & 15);
        v += bias[n];
        if (HMUL) v *= hmul[(size_t)m * 512 + n];
        C[(size_t)m * 512 + n] = v;
    }
}

// ---- mid: block (XCD-affine) owns (b, l0, l0+1); 512 threads, LDS 1.7KB ----
__global__ __launch_bounds__(512) void mid_kernel(
    const float* __restrict__ maps, const float* __restrict__ hlin,
    const float* __restrict__ W_rect, const float* __restrict__ b_rect,
    float* __restrict__ attn_out, float* __restrict__ ctx_out)
{
    __shared__ float smrow[2 * 208];
    const int tid = threadIdx.x, bx = blockIdx.x;
    const int xcd = bx & 7, idx = bx >> 3;           // idx 0..31
    const int b  = (xcd << 1) | (idx & 1);           // maps[b-pair] -> this XCD's L2
    const int l0 = (idx >> 1) * 2;                   // 0,2,..,30
    const int w = tid >> 6, lane = tid & 63;
    const int a_lo = lane * 4, a_hi = 256 + lane * 4;

    // per-lane hlin / W_rect slices (coalesced float4; post-dispatch-acquire safe)
    const float* h0p = hlin + ((size_t)b * 32 + l0) * 512;
    const float* h1p = h0p + 512;
    const float4 g0_lo = *(const float4*)(h0p + a_lo);
    const float4 g0_hi = *(const float4*)(h0p + a_hi);
    const float4 g1_lo = *(const float4*)(h1p + a_lo);
    const float4 g1_hi = *(const float4*)(h1p + a_hi);
    const float4 w_lo  = *(const float4*)(W_rect + a_lo);
    const float4 w_hi  = *(const float4*)(W_rect + a_hi);
    const float br = b_rect[0];
    const float* mb = maps + (size_t)b * 196 * 512;

    // scores: wave w owns p === w (mod 8); direct float4 loads (HBM once -> L2)
    for (int p0 = w; p0 < 196; p0 += 8) {
        const float* fr = mb + (size_t)p0 * 512;
        const float4 fa = *(const float4*)(fr + a_lo);
        const float4 fb = *(const float4*)(fr + a_hi);
        float sA = rdot4(fa, g0_lo, w_lo) + rdot4(fb, g0_hi, w_hi);
        float sB = rdot4(fa, g1_lo, w_lo) + rdot4(fb, g1_hi, w_hi);
        sA = wave_sum(sA);
        sB = wave_sum(sB);
        if (lane == 0) { smrow[p0] = sA + br; smrow[208 + p0] = sB + br; }
    }
    __syncthreads();

    // softmax: wave 0 -> l0, wave 1 -> l0+1
    if (w < 2) {
        float v[4];
        #pragma unroll
        for (int i = 0; i < 4; ++i) {
            const int p = lane + 64 * i;
            v[i] = (p < 196) ? smrow[w * 208 + p] : -INFINITY;
        }
        float m = fmaxf(fmaxf(v[0], v[1]), fmaxf(v[2], v[3]));
        for (int off = 32; off > 0; off >>= 1) m = fmaxf(m, __shfl_down(m, off));
        m = __shfl(m, 0);
        float e[4], ssum = 0.f;
        #pragma unroll
        for (int i = 0; i < 4; ++i) {
            const int p = lane + 64 * i;
            e[i] = (p < 196) ? __expf(v[i] - m) : 0.f;
            ssum += e[i];
        }
        for (int off = 32; off > 0; off >>= 1) ssum += __shfl_down(ssum, off);
        ssum = __shfl(ssum, 0);
        const float inv = 1.f / ssum;
        float* ao = attn_out + ((size_t)b * 32 + l0 + w) * 196;
        #pragma unroll
        for (int i = 0; i < 4; ++i) {
            const int p = lane + 64 * i;
            if (p < 196) {
                const float at = e[i] * inv;
                smrow[w * 208 + p] = at;
                ao[p] = at;
            }
        }
    }
    __syncthreads();

    // ctx: thread owns col d = tid; maps rows now L2-hot (same kernel, no inval)
    {
        const int d = tid;
        float a0=0.f,a1=0.f,a2=0.f,a3=0.f, c0=0.f,c1=0.f,c2=0.f,c3=0.f;
        for (int p = 0; p < 196; p += 4) {
            const float f0 = mb[(size_t)(p+0)*512 + d];
            const float f1 = mb[(size_t)(p+1)*512 + d];
            const float f2 = mb[(size_t)(p+2)*512 + d];
            const float f3 = mb[(size_t)(p+3)*512 + d];
            a0 += smrow[p+0]*f0; a1 += smrow[p+1]*f1;
            a2 += smrow[p+2]*f2; a3 += smrow[p+3]*f3;
            c0 += smrow[208+p+0]*f0; c1 += smrow[208+p+1]*f1;
            c2 += smrow[208+p+2]*f2; c3 += smrow[208+p+3]*f3;
        }
        float* cx = ctx_out + ((size_t)b * 32 + l0) * 512;
        cx[d]       = (a0 + a1) + (a2 + a3);
        cx[512 + d] = (c0 + c1) + (c2 + c3);
    }
}

extern "C" void kernel_launch(void* const* d_in, const int* in_sizes, int n_in,
                              void* d_out, int out_size, void* d_ws, size_t ws_size,
                              hipStream_t stream)
{
    const float* maps     = (const float*)d_in[0];
    const float* hiddens  = (const float*)d_in[1];
    const float* W_hidden = (const float*)d_in[2];
    const float* b_hidden = (const float*)d_in[3];
    const float* W_rect   = (const float*)d_in[4];
    const float* b_rect   = (const float*)d_in[5];
    const float* W_co     = (const float*)d_in[6];
    const float* b_co     = (const float*)d_in[7];

    float* out_co   = (float*)d_out;                    // (512,512)
    float* out_attn = out_co + (size_t)512 * 512;       // (512,196)
    float* hlin     = (float*)d_ws;                     // (512,512) fp32
    float* ctx      = hlin + (size_t)512 * 512;         // (512,512) fp32

    // 1) hlin = hiddens @ W_hidden^T + b_hidden
    hipLaunchKernelGGL((gemm_kernel<0>), dim3(256), dim3(512), 0, stream,
                       hiddens, W_hidden, b_hidden, (const float*)nullptr, hlin);
    // 2) scores -> softmax (-> out_attn) -> ctx (-> ws)
    hipLaunchKernelGGL(mid_kernel, dim3(256), dim3(512), 0, stream,
                       maps, hlin, W_rect, b_rect, out_attn, ctx);
    // 3) out = (ctx @ W_co^T + b_co) * hiddens
    hipLaunchKernelGGL((gemm_kernel<1>), dim3(256), dim3(512), 0, stream,
                       ctx, W_co, b_co, hiddens, out_co);
}